// Round 12
// baseline (423.060 us; speedup 1.0000x reference)
//
#include <hip/hip_runtime.h>
#include <hip/hip_bf16.h>
#include <stdint.h>

#define NB 2048
#define NR 10
#define ND 1024
#define NTGT (NB * (NR - 1))   /* 18432 targets */
#define INV_TEMP 20.0f

#define BM 128
#define BN 256
#define BK 64                  /* fp8: 64 B rows in LDS */
#define NKT (ND / BK)          /* 16 K-tiles */
#define TM_TILES (NB / BM)     /* 16 */
#define TN_TILES (NTGT / BN)   /* 72 */

typedef __attribute__((ext_vector_type(4))) float floatx4;
typedef __attribute__((ext_vector_type(16))) float floatx16;
typedef __attribute__((ext_vector_type(4))) int intx4;
typedef __attribute__((ext_vector_type(8))) int intx8;

#define BAR()    asm volatile("s_barrier" ::: "memory")
#define VMCNT0() asm volatile("s_waitcnt vmcnt(0)" ::: "memory")
#define VMCNT3() asm volatile("s_waitcnt vmcnt(3)" ::: "memory")

#define SCALE1 0x7F7F7F7F      /* e8m0 = 127 -> 2^0 = 1.0 in every byte */

__device__ __forceinline__ void async16(const void* g, void* l) {
  __builtin_amdgcn_global_load_lds(
      (const __attribute__((address_space(1))) unsigned int*)g,
      (__attribute__((address_space(3))) unsigned int*)l,
      16, 0, 0);
}

// ---------------------------------------------------------------------------
// Kernel 1 (fused prep): one block per b. Reads the 10 rows of b ONCE:
// computes 10 norms + 9 anchor-dots, writes normalized FP8 (e4m3) A/T rows,
// KL, pos_score. KL/pos_score stay exact fp32.
// ---------------------------------------------------------------------------
__global__ __launch_bounds__(256) void prep_kernel(
    const float* __restrict__ emb, const float* __restrict__ scores,
    unsigned char* __restrict__ A8, unsigned char* __restrict__ T8,
    float* __restrict__ pos_score, float* __restrict__ kl_out) {
  int b = blockIdx.x;
  int tid = threadIdx.x;             // float4 index within a row (256*4 = 1024)
  int wid = tid >> 6, lane = tid & 63;
  const float* base = emb + (size_t)b * NR * ND;

  float4 v[NR];
  float ss[NR], dt[NR - 1];
#pragma unroll
  for (int r = 0; r < NR; ++r) {
    v[r] = reinterpret_cast<const float4*>(base + (size_t)r * ND)[tid];
    ss[r] = v[r].x * v[r].x + v[r].y * v[r].y + v[r].z * v[r].z + v[r].w * v[r].w;
  }
#pragma unroll
  for (int t = 0; t < NR - 1; ++t)
    dt[t] = v[0].x * v[t + 1].x + v[0].y * v[t + 1].y + v[0].z * v[t + 1].z +
            v[0].w * v[t + 1].w;

#pragma unroll
  for (int off = 32; off; off >>= 1) {
#pragma unroll
    for (int r = 0; r < NR; ++r) ss[r] += __shfl_xor(ss[r], off, 64);
#pragma unroll
    for (int t = 0; t < NR - 1; ++t) dt[t] += __shfl_xor(dt[t], off, 64);
  }
  __shared__ float red[4][2 * NR - 1];
  if (lane == 0) {
#pragma unroll
    for (int r = 0; r < NR; ++r) red[wid][r] = ss[r];
#pragma unroll
    for (int t = 0; t < NR - 1; ++t) red[wid][NR + t] = dt[t];
  }
  __syncthreads();

  float inv[NR];
#pragma unroll
  for (int r = 0; r < NR; ++r) {
    float s = red[0][r] + red[1][r] + red[2][r] + red[3][r];
    inv[r] = 1.0f / fmaxf(sqrtf(s), 1e-12f);
  }

  // write normalized fp8 rows (4 bytes/thread/row)
#pragma unroll
  for (int r = 0; r < NR; ++r) {
    unsigned char* dst;
    if (r == 0)      dst = A8 + (size_t)b * ND;
    else if (r == 1) dst = T8 + (size_t)b * ND;
    else             dst = T8 + (size_t)(NB + b * 8 + (r - 2)) * ND;
    int p = 0;
    p = __builtin_amdgcn_cvt_pk_fp8_f32(v[r].x * inv[r], v[r].y * inv[r], p, false);
    p = __builtin_amdgcn_cvt_pk_fp8_f32(v[r].z * inv[r], v[r].w * inv[r], p, true);
    reinterpret_cast<int*>(dst)[tid] = p;
  }

  if (tid == 0) {
    float rs[NR - 1];
#pragma unroll
    for (int t = 0; t < NR - 1; ++t) {
      float d = red[0][NR + t] + red[1][NR + t] + red[2][NR + t] + red[3][NR + t];
      rs[t] = d * inv[0] * inv[t + 1];
    }
    float sc[NR - 1], ms = -1e30f;
#pragma unroll
    for (int k = 0; k < NR - 1; ++k) { sc[k] = scores[b * (NR - 1) + k]; ms = fmaxf(ms, sc[k]); }
    float se = 0.f;
#pragma unroll
    for (int k = 0; k < NR - 1; ++k) { sc[k] = expf(sc[k] - ms); se += sc[k]; }
    float mr = -1e30f;
#pragma unroll
    for (int k = 0; k < NR - 1; ++k) mr = fmaxf(mr, rs[k]);
    float sr = 0.f;
#pragma unroll
    for (int k = 0; k < NR - 1; ++k) sr += expf(rs[k] - mr);
    float lz = logf(sr) + mr;
    float kl = 0.f;
#pragma unroll
    for (int k = 0; k < NR - 1; ++k) {
      float ce = sc[k] / se;
      kl += ce * logf(ce) - ce * (rs[k] - lz);
    }
    kl_out[b] = kl / (float)(NR - 1);
    pos_score[b] = rs[0];
  }
}

// ---------------------------------------------------------------------------
// Kernel 2: 128x256x64 FP8 GEMM via MX-scaled mfma_scale_f32_32x32x64_f8f6f4
// (scales = 1.0 -> numerically identical to plain fp8, 2x MFMA rate).
// Triple-buffered LDS (72 KiB), counted vmcnt(3), ONE barrier per K-iter,
// 2 blocks/CU. Wave tile 64x64 = 2x2 of 32x32; 4 MFMA per K-iter per wave.
// Fragment: lane l needs logical bytes [32*(l>>5), +32) of row (l&31):
// two ds_read_b128 at swizzled units (hi*2+q)^swz -- XOR cancels against the
// pre-swizzled staging source, so logical content is exact; conflict-free
// (8 consecutive rows cover all 8 bank-quads, same proof as rounds 8/10).
// ---------------------------------------------------------------------------

// Stage A K-slice: 128 rows x 64 B = 8 KB, 1 load/thread.
__device__ __forceinline__ void stage_A8(const unsigned char* __restrict__ gtile,
                                         unsigned char* lds, int k0, int tid) {
  int lrow = tid >> 2;                 // 0..127
  int u = (tid & 3) ^ ((lrow >> 1) & 3);
  const unsigned char* src = gtile + (size_t)lrow * ND + k0 + u * 16;
  unsigned char* dst = lds + (tid & ~63) * 16;  // wave-uniform base, +lane*16B
  async16(src, dst);
}

// Stage B K-slice: 256 rows x 64 B = 16 KB, 2 loads/thread.
__device__ __forceinline__ void stage_B8(const unsigned char* __restrict__ gtile,
                                         unsigned char* lds, int k0, int tid) {
#pragma unroll
  for (int r = 0; r < 2; ++r) {
    int slot = r * 512 + tid;          // 0..1023
    int lrow = slot >> 2;              // 0..255
    int u = (slot & 3) ^ ((lrow >> 1) & 3);
    const unsigned char* src = gtile + (size_t)lrow * ND + k0 + u * 16;
    unsigned char* dst = lds + (r * 512 + (tid & ~63)) * 16;
    async16(src, dst);
  }
}

// Fragment for 32x32x64: 32 logical bytes [hi*32, +32) of `row`, as v8i32.
__device__ __forceinline__ intx8 frag32(const unsigned char* lds, int row, int hi) {
  int swz = (row >> 1) & 3;
  const unsigned char* base = lds + row * 64;
  intx4 lo = *reinterpret_cast<const intx4*>(base + ((((hi << 1) | 0) ^ swz) << 4));
  intx4 hh = *reinterpret_cast<const intx4*>(base + ((((hi << 1) | 1) ^ swz) << 4));
  intx8 r = {lo.x, lo.y, lo.z, lo.w, hh.x, hh.y, hh.z, hh.w};
  return r;
}

__global__ __launch_bounds__(512, 4) void gemm_lse_kernel(
    const unsigned char* __restrict__ A, const unsigned char* __restrict__ T,
    float* __restrict__ sumexp) {
  // 72 KiB: 3 x [As 8K][Bs 16K]
  __shared__ unsigned char smem[3 * (BM + BN) * BK];

  int bid = blockIdx.x;             // 1152 = 8 * 144
  int xcd = bid & 7;
  int j = bid >> 3;                 // 0..143
  int tn = xcd * 9 + (j >> 4);      // 9 B-panels per XCD
  int tm = j & 15;

  int tid = threadIdx.x;
  int wid = tid >> 6, lane = tid & 63;
  int wm = wid >> 2, wn = wid & 3;  // 2 x 4 waves; wave tile 64 x 64
  int l31 = lane & 31, hi = lane >> 5;

  const unsigned char* Ag = A + (size_t)tm * BM * ND;
  const unsigned char* Tg = T + (size_t)tn * BN * ND;

  floatx16 acc[2][2] = {};

  unsigned char* bufA0 = smem;
  unsigned char* bufB0 = smem + BM * BK;
  unsigned char* bufA1 = smem + (BM + BN) * BK;
  unsigned char* bufB1 = bufA1 + BM * BK;
  unsigned char* bufA2 = smem + 2 * (BM + BN) * BK;
  unsigned char* bufB2 = bufA2 + BM * BK;

  // Prologue: stage kt0 -> buf0, kt1 -> buf1; wait kt0 (3 outstanding = kt1).
  stage_A8(Ag, bufA0, 0, tid);
  stage_B8(Tg, bufB0, 0, tid);
  stage_A8(Ag, bufA1, BK, tid);
  stage_B8(Tg, bufB1, BK, tid);
  VMCNT3();
  BAR();

  const unsigned char* Acur = bufA0;  const unsigned char* Bcur = bufB0;
  unsigned char* Anxt = bufA1;        unsigned char* Bnxt = bufB1;   // kt s+1
  unsigned char* Afar = bufA2;        unsigned char* Bfar = bufB2;   // kt s+2 target

  for (int s = 0; s < NKT; ++s) {
    const int kn = ((s + 2) & (NKT - 1)) * BK;  // wrap: last 2 iters stage into
                                                // dead buffers (harmless)
    // stage kt s+2 (3 loads/thread, issued first for max slack)
    stage_A8(Ag, Afar, kn, tid);
    stage_B8(Tg, Bfar, kn, tid);

    intx8 bF[2];
#pragma unroll
    for (int n = 0; n < 2; ++n)
      bF[n] = frag32(Bcur, wn * 64 + n * 32 + l31, hi);

    __builtin_amdgcn_s_setprio(1);
#pragma unroll
    for (int m = 0; m < 2; ++m) {
      intx8 aF = frag32(Acur, wm * 64 + m * 32 + l31, hi);
#pragma unroll
      for (int n = 0; n < 2; ++n)
        acc[m][n] = __builtin_amdgcn_mfma_scale_f32_32x32x64_f8f6f4(
            aF, bF[n], acc[m][n], 0, 0, 0, SCALE1, 0, SCALE1);
    }
    __builtin_amdgcn_s_setprio(0);

    VMCNT3();   // kt s+1 fully landed (its 3 loads issued one full iter ago)
    BAR();

    // rotate buffers
    unsigned char* ta = (unsigned char*)Acur;  unsigned char* tb = (unsigned char*)Bcur;
    Acur = Anxt;  Bcur = Bnxt;
    Anxt = Afar;  Bnxt = Bfar;
    Afar = ta;    Bfar = tb;
  }

  VMCNT0();  // drain wrapped final stages before LDS is released

  // Epilogue: 32x32 C layout: col = lane&31 (within tile), row = (j&3) +
  // 8*(j>>2) + 4*hi. Sum the two n-tiles' exp in-register (covers the wave's
  // 64 cols of that row), reduce across the 32-lane half, one atomic per row.
#pragma unroll
  for (int m = 0; m < 2; ++m) {
#pragma unroll
    for (int j2 = 0; j2 < 16; ++j2) {
      float s = __expf(acc[m][0][j2] * INV_TEMP) + __expf(acc[m][1][j2] * INV_TEMP);
      s += __shfl_xor(s, 1, 64);
      s += __shfl_xor(s, 2, 64);
      s += __shfl_xor(s, 4, 64);
      s += __shfl_xor(s, 8, 64);
      s += __shfl_xor(s, 16, 64);
      if (l31 == 0) {
        int grow = tm * BM + wm * 64 + m * 32 + (j2 & 3) + 8 * (j2 >> 2) + 4 * hi;
        atomicAdd(&sumexp[grow], s);
      }
    }
  }
}

// ---------------------------------------------------------------------------
// Kernel 3: final scalar reduction.
// ---------------------------------------------------------------------------
__global__ __launch_bounds__(256) void finalize_kernel(
    const float* __restrict__ sumexp, const float* __restrict__ pos_score,
    const float* __restrict__ kl, float* __restrict__ out) {
  int tid = threadIdx.x;
  float kls = 0.f, ces = 0.f;
  for (int i = tid; i < NB; i += 256) {
    kls += kl[i];
    ces += logf(sumexp[i]) - pos_score[i] * INV_TEMP;
  }
#pragma unroll
  for (int off = 32; off; off >>= 1) {
    kls += __shfl_xor(kls, off, 64);
    ces += __shfl_xor(ces, off, 64);
  }
  __shared__ float sk[4], se4[4];
  int wid = tid >> 6, lane = tid & 63;
  if (lane == 0) { sk[wid] = kls; se4[wid] = ces; }
  __syncthreads();
  if (tid == 0) {
    float k4 = sk[0] + sk[1] + sk[2] + sk[3];
    float e4 = se4[0] + se4[1] + se4[2] + se4[3];
    out[0] = 0.5f * (k4 / (float)NB) + 1.0f * (e4 / (float)NB);
  }
}

extern "C" void kernel_launch(void* const* d_in, const int* in_sizes, int n_in,
                              void* d_out, int out_size, void* d_ws, size_t ws_size,
                              hipStream_t stream) {
  const float* emb = (const float*)d_in[0];
  const float* scores = (const float*)d_in[1];
  float* out = (float*)d_out;

  char* ws = (char*)d_ws;
  size_t offA = 0;
  size_t offT = offA + (size_t)NB * ND;          // fp8: 1 B/elem
  size_t offSum = offT + (size_t)NTGT * ND;
  size_t offPos = offSum + (size_t)NB * 4;
  size_t offKl = offPos + (size_t)NB * 4;

  unsigned char* A8 = (unsigned char*)(ws + offA);
  unsigned char* T8 = (unsigned char*)(ws + offT);
  float* sumexp = (float*)(ws + offSum);
  float* pos_score = (float*)(ws + offPos);
  float* kl = (float*)(ws + offKl);

  hipMemsetAsync(sumexp, 0, (size_t)NB * 4, stream);
  prep_kernel<<<NB, 256, 0, stream>>>(emb, scores, A8, T8, pos_score, kl);
  gemm_lse_kernel<<<dim3(TM_TILES * TN_TILES), 512, 0, stream>>>(A8, T8, sumexp);
  finalize_kernel<<<1, 256, 0, stream>>>(sumexp, pos_score, kl, out);
}

// Round 13
// 241.060 us; speedup vs baseline: 1.7550x; 1.7550x over previous
//
#include <hip/hip_runtime.h>
#include <hip/hip_bf16.h>
#include <stdint.h>

#define NB 2048
#define NR 10
#define ND 1024
#define NTGT (NB * (NR - 1))   /* 18432 targets */
#define INV_TEMP 20.0f

#define BM 128
#define BN 256
#define BK 64                  /* fp8: 64 B rows in LDS */
#define NKT (ND / BK)          /* 16 K-tiles */
#define TM_TILES (NB / BM)     /* 16 */
#define TN_TILES (NTGT / BN)   /* 72 */

typedef __attribute__((ext_vector_type(4))) float floatx4;
typedef __attribute__((ext_vector_type(16))) float floatx16;
typedef __attribute__((ext_vector_type(4))) int intx4;
typedef __attribute__((ext_vector_type(8))) int intx8;

#define BAR()    asm volatile("s_barrier" ::: "memory")
#define VMCNT0() asm volatile("s_waitcnt vmcnt(0)" ::: "memory")
#define VMCNT3() asm volatile("s_waitcnt vmcnt(3)" ::: "memory")

#define SCALE1 0x7F7F7F7F      /* e8m0 = 127 -> 2^0 = 1.0 in every byte */

__device__ __forceinline__ void async16(const void* g, void* l) {
  __builtin_amdgcn_global_load_lds(
      (const __attribute__((address_space(1))) unsigned int*)g,
      (__attribute__((address_space(3))) unsigned int*)l,
      16, 0, 0);
}

// ---------------------------------------------------------------------------
// Kernel 1 (fused prep): one block per b. Reads the 10 rows of b ONCE:
// computes 10 norms + 9 anchor-dots, writes normalized FP8 (e4m3) A/T rows,
// KL, pos_score. KL/pos_score stay exact fp32.
// ---------------------------------------------------------------------------
__global__ __launch_bounds__(256) void prep_kernel(
    const float* __restrict__ emb, const float* __restrict__ scores,
    unsigned char* __restrict__ A8, unsigned char* __restrict__ T8,
    float* __restrict__ pos_score, float* __restrict__ kl_out) {
  int b = blockIdx.x;
  int tid = threadIdx.x;             // float4 index within a row (256*4 = 1024)
  int wid = tid >> 6, lane = tid & 63;
  const float* base = emb + (size_t)b * NR * ND;

  float4 v[NR];
  float ss[NR], dt[NR - 1];
#pragma unroll
  for (int r = 0; r < NR; ++r) {
    v[r] = reinterpret_cast<const float4*>(base + (size_t)r * ND)[tid];
    ss[r] = v[r].x * v[r].x + v[r].y * v[r].y + v[r].z * v[r].z + v[r].w * v[r].w;
  }
#pragma unroll
  for (int t = 0; t < NR - 1; ++t)
    dt[t] = v[0].x * v[t + 1].x + v[0].y * v[t + 1].y + v[0].z * v[t + 1].z +
            v[0].w * v[t + 1].w;

#pragma unroll
  for (int off = 32; off; off >>= 1) {
#pragma unroll
    for (int r = 0; r < NR; ++r) ss[r] += __shfl_xor(ss[r], off, 64);
#pragma unroll
    for (int t = 0; t < NR - 1; ++t) dt[t] += __shfl_xor(dt[t], off, 64);
  }
  __shared__ float red[4][2 * NR - 1];
  if (lane == 0) {
#pragma unroll
    for (int r = 0; r < NR; ++r) red[wid][r] = ss[r];
#pragma unroll
    for (int t = 0; t < NR - 1; ++t) red[wid][NR + t] = dt[t];
  }
  __syncthreads();

  float inv[NR];
#pragma unroll
  for (int r = 0; r < NR; ++r) {
    float s = red[0][r] + red[1][r] + red[2][r] + red[3][r];
    inv[r] = 1.0f / fmaxf(sqrtf(s), 1e-12f);
  }

  // write normalized fp8 rows (4 bytes/thread/row)
#pragma unroll
  for (int r = 0; r < NR; ++r) {
    unsigned char* dst;
    if (r == 0)      dst = A8 + (size_t)b * ND;
    else if (r == 1) dst = T8 + (size_t)b * ND;
    else             dst = T8 + (size_t)(NB + b * 8 + (r - 2)) * ND;
    int p = 0;
    p = __builtin_amdgcn_cvt_pk_fp8_f32(v[r].x * inv[r], v[r].y * inv[r], p, false);
    p = __builtin_amdgcn_cvt_pk_fp8_f32(v[r].z * inv[r], v[r].w * inv[r], p, true);
    reinterpret_cast<int*>(dst)[tid] = p;
  }

  if (tid == 0) {
    float rs[NR - 1];
#pragma unroll
    for (int t = 0; t < NR - 1; ++t) {
      float d = red[0][NR + t] + red[1][NR + t] + red[2][NR + t] + red[3][NR + t];
      rs[t] = d * inv[0] * inv[t + 1];
    }
    float sc[NR - 1], ms = -1e30f;
#pragma unroll
    for (int k = 0; k < NR - 1; ++k) { sc[k] = scores[b * (NR - 1) + k]; ms = fmaxf(ms, sc[k]); }
    float se = 0.f;
#pragma unroll
    for (int k = 0; k < NR - 1; ++k) { sc[k] = expf(sc[k] - ms); se += sc[k]; }
    float mr = -1e30f;
#pragma unroll
    for (int k = 0; k < NR - 1; ++k) mr = fmaxf(mr, rs[k]);
    float sr = 0.f;
#pragma unroll
    for (int k = 0; k < NR - 1; ++k) sr += expf(rs[k] - mr);
    float lz = logf(sr) + mr;
    float kl = 0.f;
#pragma unroll
    for (int k = 0; k < NR - 1; ++k) {
      float ce = sc[k] / se;
      kl += ce * logf(ce) - ce * (rs[k] - lz);
    }
    kl_out[b] = kl / (float)(NR - 1);
    pos_score[b] = rs[0];
  }
}

// ---------------------------------------------------------------------------
// Kernel 2: 128x256x64 FP8 GEMM via MX-scaled mfma_scale_f32_32x32x64_f8f6f4
// (scales = 1.0 -> numerically identical to plain fp8, 2x MFMA rate; verified
// correct in round 12, absmax 0). Triple-buffered LDS (72 KiB), counted
// vmcnt(3), ONE barrier per K-iter. __launch_bounds__(512) WITHOUT a
// min-waves clause: round 12's (512,4) forced a 128-reg cap -> acc spilled
// to scratch (748 MB writes). ~110-130 regs still yields 4 waves/SIMD.
// All addressing (staging src/dst, fragment LDS offsets) precomputed once.
// ---------------------------------------------------------------------------

__global__ __launch_bounds__(512) void gemm_lse_kernel(
    const unsigned char* __restrict__ A, const unsigned char* __restrict__ T,
    float* __restrict__ sumexp) {
  // 72 KiB: 3 x [As 8K][Bs 16K]
  __shared__ unsigned char smem[3 * (BM + BN) * BK];

  int bid = blockIdx.x;             // 1152 = 8 * 144
  int xcd = bid & 7;
  int j = bid >> 3;                 // 0..143
  int tn = xcd * 9 + (j >> 4);      // 9 B-panels per XCD
  int tm = j & 15;

  int tid = threadIdx.x;
  int wid = tid >> 6, lane = tid & 63;
  int wm = wid >> 2, wn = wid & 3;  // 2 x 4 waves; wave tile 64 x 64
  int l31 = lane & 31, hi = lane >> 5;

  const unsigned char* Ag = A + (size_t)tm * BM * ND;
  const unsigned char* Tg = T + (size_t)tn * BN * ND;

  // ---- precomputed staging addressing (loop-invariant) ----
  // A: 1 load/thread. lrow = tid>>2, unit u = (tid&3)^((lrow>>1)&3).
  int a_lrow = tid >> 2;
  int a_goff = a_lrow * ND + (((tid & 3) ^ ((a_lrow >> 1) & 3)) << 4);
  int a_doff = (tid & ~63) * 16;
  // B: 2 loads/thread. slot r*512+tid.
  int b_lrow0 = tid >> 2;                       // slot0 = tid
  int b_goff0 = b_lrow0 * ND + (((tid & 3) ^ ((b_lrow0 >> 1) & 3)) << 4);
  int b_doff0 = (tid & ~63) * 16;
  int b_lrow1 = (512 + tid) >> 2;               // slot1 = 512 + tid
  int b_goff1 = b_lrow1 * ND + ((((512 + tid) & 3) ^ ((b_lrow1 >> 1) & 3)) << 4);
  int b_doff1 = (512 + (tid & ~63)) * 16;

  // ---- precomputed fragment LDS byte offsets (relative to buffer base) ----
  // Fragment row for A tile m: wm*64 + m*32 + l31; for B tile n: wn*64 + n*32 + l31.
  // lane reads logical units {hi*2, hi*2+1} XOR swz(row).
  int offA[2][2], offB[2][2];
#pragma unroll
  for (int m = 0; m < 2; ++m) {
    int row = wm * 64 + m * 32 + l31;
    int swz = (row >> 1) & 3;
    offA[m][0] = row * 64 + ((((hi << 1) | 0) ^ swz) << 4);
    offA[m][1] = row * 64 + ((((hi << 1) | 1) ^ swz) << 4);
  }
#pragma unroll
  for (int n = 0; n < 2; ++n) {
    int row = wn * 64 + n * 32 + l31;
    int swz = (row >> 1) & 3;
    offB[n][0] = row * 64 + ((((hi << 1) | 0) ^ swz) << 4);
    offB[n][1] = row * 64 + ((((hi << 1) | 1) ^ swz) << 4);
  }

  floatx16 acc[2][2] = {};

  unsigned char* bufA0 = smem;
  unsigned char* bufB0 = smem + BM * BK;
  unsigned char* bufA1 = smem + (BM + BN) * BK;
  unsigned char* bufB1 = bufA1 + BM * BK;
  unsigned char* bufA2 = smem + 2 * (BM + BN) * BK;
  unsigned char* bufB2 = bufA2 + BM * BK;

  // Prologue: stage kt0 -> buf0, kt1 -> buf1; wait kt0 (3 outstanding = kt1).
  async16(Ag + a_goff, bufA0 + a_doff);
  async16(Tg + b_goff0, bufB0 + b_doff0);
  async16(Tg + b_goff1, bufB0 + b_doff1);
  async16(Ag + a_goff + BK, bufA1 + a_doff);
  async16(Tg + b_goff0 + BK, bufB1 + b_doff0);
  async16(Tg + b_goff1 + BK, bufB1 + b_doff1);
  VMCNT3();
  BAR();

  const unsigned char* Acur = bufA0;  const unsigned char* Bcur = bufB0;
  unsigned char* Anxt = bufA1;        unsigned char* Bnxt = bufB1;   // kt s+1
  unsigned char* Afar = bufA2;        unsigned char* Bfar = bufB2;   // kt s+2 target

  for (int s = 0; s < NKT; ++s) {
    const int kn = ((s + 2) & (NKT - 1)) * BK;  // wrap: last 2 iters stage into
                                                // dead buffers (harmless)
    // stage kt s+2 (3 loads/thread, issued first for max slack)
    async16(Ag + a_goff + kn, Afar + a_doff);
    async16(Tg + b_goff0 + kn, Bfar + b_doff0);
    async16(Tg + b_goff1 + kn, Bfar + b_doff1);

    intx8 aF[2], bF[2];
#pragma unroll
    for (int m = 0; m < 2; ++m) {
      intx4 lo = *reinterpret_cast<const intx4*>(Acur + offA[m][0]);
      intx4 hh = *reinterpret_cast<const intx4*>(Acur + offA[m][1]);
      aF[m] = intx8{lo.x, lo.y, lo.z, lo.w, hh.x, hh.y, hh.z, hh.w};
    }
#pragma unroll
    for (int n = 0; n < 2; ++n) {
      intx4 lo = *reinterpret_cast<const intx4*>(Bcur + offB[n][0]);
      intx4 hh = *reinterpret_cast<const intx4*>(Bcur + offB[n][1]);
      bF[n] = intx8{lo.x, lo.y, lo.z, lo.w, hh.x, hh.y, hh.z, hh.w};
    }

    __builtin_amdgcn_s_setprio(1);
#pragma unroll
    for (int m = 0; m < 2; ++m)
#pragma unroll
      for (int n = 0; n < 2; ++n)
        acc[m][n] = __builtin_amdgcn_mfma_scale_f32_32x32x64_f8f6f4(
            aF[m], bF[n], acc[m][n], 0, 0, 0, SCALE1, 0, SCALE1);
    __builtin_amdgcn_s_setprio(0);

    VMCNT3();   // kt s+1 fully landed (its 3 loads issued one full iter ago)
    BAR();

    // rotate buffers
    unsigned char* ta = (unsigned char*)Acur;  unsigned char* tb = (unsigned char*)Bcur;
    Acur = Anxt;  Bcur = Bnxt;
    Anxt = Afar;  Bnxt = Bfar;
    Afar = ta;    Bfar = tb;
  }

  VMCNT0();  // drain wrapped final stages before LDS is released

  // Epilogue: 32x32 C layout: col = lane&31 (within tile), row = (j&3) +
  // 8*(j>>2) + 4*hi. Sum the two n-tiles' exp in-register, reduce across the
  // 32-lane half, one atomic per row. (Verified correct in round 12.)
#pragma unroll
  for (int m = 0; m < 2; ++m) {
#pragma unroll
    for (int j2 = 0; j2 < 16; ++j2) {
      float s = __expf(acc[m][0][j2] * INV_TEMP) + __expf(acc[m][1][j2] * INV_TEMP);
      s += __shfl_xor(s, 1, 64);
      s += __shfl_xor(s, 2, 64);
      s += __shfl_xor(s, 4, 64);
      s += __shfl_xor(s, 8, 64);
      s += __shfl_xor(s, 16, 64);
      if (l31 == 0) {
        int grow = tm * BM + wm * 64 + m * 32 + (j2 & 3) + 8 * (j2 >> 2) + 4 * hi;
        atomicAdd(&sumexp[grow], s);
      }
    }
  }
}

// ---------------------------------------------------------------------------
// Kernel 3: final scalar reduction.
// ---------------------------------------------------------------------------
__global__ __launch_bounds__(256) void finalize_kernel(
    const float* __restrict__ sumexp, const float* __restrict__ pos_score,
    const float* __restrict__ kl, float* __restrict__ out) {
  int tid = threadIdx.x;
  float kls = 0.f, ces = 0.f;
  for (int i = tid; i < NB; i += 256) {
    kls += kl[i];
    ces += logf(sumexp[i]) - pos_score[i] * INV_TEMP;
  }
#pragma unroll
  for (int off = 32; off; off >>= 1) {
    kls += __shfl_xor(kls, off, 64);
    ces += __shfl_xor(ces, off, 64);
  }
  __shared__ float sk[4], se4[4];
  int wid = tid >> 6, lane = tid & 63;
  if (lane == 0) { sk[wid] = kls; se4[wid] = ces; }
  __syncthreads();
  if (tid == 0) {
    float k4 = sk[0] + sk[1] + sk[2] + sk[3];
    float e4 = se4[0] + se4[1] + se4[2] + se4[3];
    out[0] = 0.5f * (k4 / (float)NB) + 1.0f * (e4 / (float)NB);
  }
}

extern "C" void kernel_launch(void* const* d_in, const int* in_sizes, int n_in,
                              void* d_out, int out_size, void* d_ws, size_t ws_size,
                              hipStream_t stream) {
  const float* emb = (const float*)d_in[0];
  const float* scores = (const float*)d_in[1];
  float* out = (float*)d_out;

  char* ws = (char*)d_ws;
  size_t offA = 0;
  size_t offT = offA + (size_t)NB * ND;          // fp8: 1 B/elem
  size_t offSum = offT + (size_t)NTGT * ND;
  size_t offPos = offSum + (size_t)NB * 4;
  size_t offKl = offPos + (size_t)NB * 4;

  unsigned char* A8 = (unsigned char*)(ws + offA);
  unsigned char* T8 = (unsigned char*)(ws + offT);
  float* sumexp = (float*)(ws + offSum);
  float* pos_score = (float*)(ws + offPos);
  float* kl = (float*)(ws + offKl);

  hipMemsetAsync(sumexp, 0, (size_t)NB * 4, stream);
  prep_kernel<<<NB, 256, 0, stream>>>(emb, scores, A8, T8, pos_score, kl);
  gemm_lse_kernel<<<dim3(TM_TILES * TN_TILES), 512, 0, stream>>>(A8, T8, sumexp);
  finalize_kernel<<<1, 256, 0, stream>>>(sumexp, pos_score, kl, out);
}

// Round 14
// 85.873 us; speedup vs baseline: 4.9266x; 2.8072x over previous
//
#include <hip/hip_runtime.h>
#include <hip/hip_bf16.h>
#include <stdint.h>

#define NB 2048
#define NR 10
#define ND 1024
#define NTGT (NB * (NR - 1))   /* 18432 targets */
#define INV_TEMP 20.0f

#define BM 128
#define BN 256
#define BK 64                  /* fp8: 64 B rows in LDS */
#define NKT (ND / BK)          /* 16 K-tiles */
#define TM_TILES (NB / BM)     /* 16 */
#define TN_TILES (NTGT / BN)   /* 72 */

typedef __attribute__((ext_vector_type(4))) float floatx4;
typedef __attribute__((ext_vector_type(2))) long longx2;

#define BAR()    asm volatile("s_barrier" ::: "memory")
#define VMCNT0() asm volatile("s_waitcnt vmcnt(0)" ::: "memory")
#define VMCNT3() asm volatile("s_waitcnt vmcnt(3)" ::: "memory")

__device__ __forceinline__ void async16(const void* g, void* l) {
  __builtin_amdgcn_global_load_lds(
      (const __attribute__((address_space(1))) unsigned int*)g,
      (__attribute__((address_space(3))) unsigned int*)l,
      16, 0, 0);
}

// ---------------------------------------------------------------------------
// Kernel 1 (fused prep): one block per b. Reads the 10 rows of b ONCE:
// computes 10 norms + 9 anchor-dots, writes normalized FP8 (e4m3) A/T rows,
// KL, pos_score. Also zeroes sumexp[b] (replaces the memset dispatch; prep
// completes before the GEMM launches on the same stream).
// ---------------------------------------------------------------------------
__global__ __launch_bounds__(256) void prep_kernel(
    const float* __restrict__ emb, const float* __restrict__ scores,
    unsigned char* __restrict__ A8, unsigned char* __restrict__ T8,
    float* __restrict__ pos_score, float* __restrict__ kl_out,
    float* __restrict__ sumexp) {
  int b = blockIdx.x;
  int tid = threadIdx.x;             // float4 index within a row (256*4 = 1024)
  int wid = tid >> 6, lane = tid & 63;
  const float* base = emb + (size_t)b * NR * ND;

  if (tid == 32) sumexp[b] = 0.0f;   // fused memset (lane off the hot path)

  float4 v[NR];
  float ss[NR], dt[NR - 1];
#pragma unroll
  for (int r = 0; r < NR; ++r) {
    v[r] = reinterpret_cast<const float4*>(base + (size_t)r * ND)[tid];
    ss[r] = v[r].x * v[r].x + v[r].y * v[r].y + v[r].z * v[r].z + v[r].w * v[r].w;
  }
#pragma unroll
  for (int t = 0; t < NR - 1; ++t)
    dt[t] = v[0].x * v[t + 1].x + v[0].y * v[t + 1].y + v[0].z * v[t + 1].z +
            v[0].w * v[t + 1].w;

#pragma unroll
  for (int off = 32; off; off >>= 1) {
#pragma unroll
    for (int r = 0; r < NR; ++r) ss[r] += __shfl_xor(ss[r], off, 64);
#pragma unroll
    for (int t = 0; t < NR - 1; ++t) dt[t] += __shfl_xor(dt[t], off, 64);
  }
  __shared__ float red[4][2 * NR - 1];
  if (lane == 0) {
#pragma unroll
    for (int r = 0; r < NR; ++r) red[wid][r] = ss[r];
#pragma unroll
    for (int t = 0; t < NR - 1; ++t) red[wid][NR + t] = dt[t];
  }
  __syncthreads();

  float inv[NR];
#pragma unroll
  for (int r = 0; r < NR; ++r) {
    float s = red[0][r] + red[1][r] + red[2][r] + red[3][r];
    inv[r] = 1.0f / fmaxf(sqrtf(s), 1e-12f);
  }

  // write normalized fp8 rows (4 bytes/thread/row)
#pragma unroll
  for (int r = 0; r < NR; ++r) {
    unsigned char* dst;
    if (r == 0)      dst = A8 + (size_t)b * ND;
    else if (r == 1) dst = T8 + (size_t)b * ND;
    else             dst = T8 + (size_t)(NB + b * 8 + (r - 2)) * ND;
    int p = 0;
    p = __builtin_amdgcn_cvt_pk_fp8_f32(v[r].x * inv[r], v[r].y * inv[r], p, false);
    p = __builtin_amdgcn_cvt_pk_fp8_f32(v[r].z * inv[r], v[r].w * inv[r], p, true);
    reinterpret_cast<int*>(dst)[tid] = p;
  }

  if (tid == 0) {
    float rs[NR - 1];
#pragma unroll
    for (int t = 0; t < NR - 1; ++t) {
      float d = red[0][NR + t] + red[1][NR + t] + red[2][NR + t] + red[3][NR + t];
      rs[t] = d * inv[0] * inv[t + 1];
    }
    float sc[NR - 1], ms = -1e30f;
#pragma unroll
    for (int k = 0; k < NR - 1; ++k) { sc[k] = scores[b * (NR - 1) + k]; ms = fmaxf(ms, sc[k]); }
    float se = 0.f;
#pragma unroll
    for (int k = 0; k < NR - 1; ++k) { sc[k] = expf(sc[k] - ms); se += sc[k]; }
    float mr = -1e30f;
#pragma unroll
    for (int k = 0; k < NR - 1; ++k) mr = fmaxf(mr, rs[k]);
    float sr = 0.f;
#pragma unroll
    for (int k = 0; k < NR - 1; ++k) sr += expf(rs[k] - mr);
    float lz = logf(sr) + mr;
    float kl = 0.f;
#pragma unroll
    for (int k = 0; k < NR - 1; ++k) {
      float ce = sc[k] / se;
      kl += ce * logf(ce) - ce * (rs[k] - lz);
    }
    kl_out[b] = kl / (float)(NR - 1);
    pos_score[b] = rs[0];
  }
}

// ---------------------------------------------------------------------------
// Kernel 2: 128x256x64 FP8 (e4m3) GEMM + sum-exp epilogue, 2 blocks/CU.
// (Round-11 proven config: gemm 63.6 us, VGPR 64, 0 conflicts, no spill.)
// TRIPLE-buffered LDS (72 KiB), counted vmcnt(3), ONE barrier per K-iter.
// iter s: stage kt s+2 -> far buffer; read kt s; 32 MFMA; vmcnt(3)
// (= kt s+1 landed, issued a full iter ago); s_barrier; rotate.
// ---------------------------------------------------------------------------

// Stage A K-slice: 128 rows x 64 B = 8 KB, 1 load/thread.
__device__ __forceinline__ void stage_A8(const unsigned char* __restrict__ gtile,
                                         unsigned char* lds, int k0, int tid) {
  int lrow = tid >> 2;                 // 0..127
  int u = (tid & 3) ^ ((lrow >> 1) & 3);
  const unsigned char* src = gtile + (size_t)lrow * ND + k0 + u * 16;
  unsigned char* dst = lds + (tid & ~63) * 16;  // wave-uniform base, +lane*16B
  async16(src, dst);
}

// Stage B K-slice: 256 rows x 64 B = 16 KB, 2 loads/thread.
__device__ __forceinline__ void stage_B8(const unsigned char* __restrict__ gtile,
                                         unsigned char* lds, int k0, int tid) {
#pragma unroll
  for (int r = 0; r < 2; ++r) {
    int slot = r * 512 + tid;          // 0..1023
    int lrow = slot >> 2;              // 0..255
    int u = (slot & 3) ^ ((lrow >> 1) & 3);
    const unsigned char* src = gtile + (size_t)lrow * ND + k0 + u * 16;
    unsigned char* dst = lds + (r * 512 + (tid & ~63)) * 16;
    async16(src, dst);
  }
}

// Swizzled fragment-pair read: one b128; .x = kk0 (bytes lq*16..+7),
// .y = kk1 (bytes lq*16+8..+15). k-permutation invariance: both A and B use
// the same physical-k relabeling, so the dot product is unchanged.
__device__ __forceinline__ longx2 frag8(const unsigned char* lds, int row, int lq) {
  int byte = row * 64 + ((lq * 16) ^ (((row >> 1) & 3) << 4));
  return *reinterpret_cast<const longx2*>(lds + byte);
}

__global__ __launch_bounds__(512, 4) void gemm_lse_kernel(
    const unsigned char* __restrict__ A, const unsigned char* __restrict__ T,
    float* __restrict__ sumexp) {
  // 72 KiB: 3 x [As 8K][Bs 16K]
  __shared__ unsigned char smem[3 * (BM + BN) * BK];

  int bid = blockIdx.x;             // 1152 = 8 * 144
  int xcd = bid & 7;
  int j = bid >> 3;                 // 0..143
  int tn = xcd * 9 + (j >> 4);      // 9 B-panels per XCD
  int tm = j & 15;

  int tid = threadIdx.x;
  int wid = tid >> 6, lane = tid & 63;
  int wm = wid >> 2, wn = wid & 3;  // 2 x 4 waves; wave tile 64 x 64
  int lrow = lane & 15, lq = lane >> 4;

  const unsigned char* Ag = A + (size_t)tm * BM * ND;
  const unsigned char* Tg = T + (size_t)tn * BN * ND;

  floatx4 acc[4][4] = {};

  unsigned char* bufA0 = smem;
  unsigned char* bufB0 = smem + BM * BK;
  unsigned char* bufA1 = smem + (BM + BN) * BK;
  unsigned char* bufB1 = bufA1 + BM * BK;
  unsigned char* bufA2 = smem + 2 * (BM + BN) * BK;
  unsigned char* bufB2 = bufA2 + BM * BK;

  // Prologue: stage kt0 -> buf0, kt1 -> buf1; wait kt0 (3 outstanding = kt1).
  stage_A8(Ag, bufA0, 0, tid);
  stage_B8(Tg, bufB0, 0, tid);
  stage_A8(Ag, bufA1, BK, tid);
  stage_B8(Tg, bufB1, BK, tid);
  VMCNT3();
  BAR();

  const unsigned char* Acur = bufA0;  const unsigned char* Bcur = bufB0;
  unsigned char* Anxt = bufA1;        unsigned char* Bnxt = bufB1;   // kt s+1
  unsigned char* Afar = bufA2;        unsigned char* Bfar = bufB2;   // kt s+2 target

  for (int s = 0; s < NKT; ++s) {
    const int kn = ((s + 2) & (NKT - 1)) * BK;  // wrap: last 2 iters stage into
                                                // dead buffers (harmless)
    // stage kt s+2 (3 loads/thread, issued first for max slack)
    stage_A8(Ag, Afar, kn, tid);
    stage_B8(Tg, Bfar, kn, tid);

    longx2 aF[4], bF[4];
#pragma unroll
    for (int m = 0; m < 4; ++m)
      aF[m] = frag8(Acur, wm * 64 + m * 16 + lrow, lq);
#pragma unroll
    for (int n = 0; n < 4; ++n)
      bF[n] = frag8(Bcur, wn * 64 + n * 16 + lrow, lq);

    __builtin_amdgcn_s_setprio(1);
#pragma unroll
    for (int m = 0; m < 4; ++m)
#pragma unroll
      for (int n = 0; n < 4; ++n) {
        acc[m][n] = __builtin_amdgcn_mfma_f32_16x16x32_fp8_fp8(aF[m].x, bF[n].x, acc[m][n], 0, 0, 0);
        acc[m][n] = __builtin_amdgcn_mfma_f32_16x16x32_fp8_fp8(aF[m].y, bF[n].y, acc[m][n], 0, 0, 0);
      }
    __builtin_amdgcn_s_setprio(0);

    VMCNT3();   // kt s+1 fully landed (its 3 loads issued one full iter ago)
    BAR();

    // rotate buffers
    unsigned char* ta = (unsigned char*)Acur;  unsigned char* tb = (unsigned char*)Bcur;
    Acur = Anxt;  Bcur = Bnxt;
    Anxt = Afar;  Bnxt = Bfar;
    Afar = ta;    Bfar = tb;
  }

  VMCNT0();  // drain wrapped final stages before LDS is released

  // Epilogue: per C-row partial sum of exp(sim*20) over this block's 256 cols.
#pragma unroll
  for (int m = 0; m < 4; ++m) {
#pragma unroll
    for (int j2 = 0; j2 < 4; ++j2) {
      float s = __expf(acc[m][0][j2] * INV_TEMP) + __expf(acc[m][1][j2] * INV_TEMP) +
                __expf(acc[m][2][j2] * INV_TEMP) + __expf(acc[m][3][j2] * INV_TEMP);
      s += __shfl_xor(s, 1, 64);
      s += __shfl_xor(s, 2, 64);
      s += __shfl_xor(s, 4, 64);
      s += __shfl_xor(s, 8, 64);
      if (lrow == 0) {
        int grow = tm * BM + wm * 64 + m * 16 + lq * 4 + j2;
        atomicAdd(&sumexp[grow], s);
      }
    }
  }
}

// ---------------------------------------------------------------------------
// Kernel 3: final scalar reduction.
// ---------------------------------------------------------------------------
__global__ __launch_bounds__(256) void finalize_kernel(
    const float* __restrict__ sumexp, const float* __restrict__ pos_score,
    const float* __restrict__ kl, float* __restrict__ out) {
  int tid = threadIdx.x;
  float kls = 0.f, ces = 0.f;
  for (int i = tid; i < NB; i += 256) {
    kls += kl[i];
    ces += logf(sumexp[i]) - pos_score[i] * INV_TEMP;
  }
#pragma unroll
  for (int off = 32; off; off >>= 1) {
    kls += __shfl_xor(kls, off, 64);
    ces += __shfl_xor(ces, off, 64);
  }
  __shared__ float sk[4], se4[4];
  int wid = tid >> 6, lane = tid & 63;
  if (lane == 0) { sk[wid] = kls; se4[wid] = ces; }
  __syncthreads();
  if (tid == 0) {
    float k4 = sk[0] + sk[1] + sk[2] + sk[3];
    float e4 = se4[0] + se4[1] + se4[2] + se4[3];
    out[0] = 0.5f * (k4 / (float)NB) + 1.0f * (e4 / (float)NB);
  }
}

extern "C" void kernel_launch(void* const* d_in, const int* in_sizes, int n_in,
                              void* d_out, int out_size, void* d_ws, size_t ws_size,
                              hipStream_t stream) {
  const float* emb = (const float*)d_in[0];
  const float* scores = (const float*)d_in[1];
  float* out = (float*)d_out;

  char* ws = (char*)d_ws;
  size_t offA = 0;
  size_t offT = offA + (size_t)NB * ND;          // fp8: 1 B/elem
  size_t offSum = offT + (size_t)NTGT * ND;
  size_t offPos = offSum + (size_t)NB * 4;
  size_t offKl = offPos + (size_t)NB * 4;

  unsigned char* A8 = (unsigned char*)(ws + offA);
  unsigned char* T8 = (unsigned char*)(ws + offT);
  float* sumexp = (float*)(ws + offSum);
  float* pos_score = (float*)(ws + offPos);
  float* kl = (float*)(ws + offKl);

  prep_kernel<<<NB, 256, 0, stream>>>(emb, scores, A8, T8, pos_score, kl, sumexp);
  gemm_lse_kernel<<<dim3(TM_TILES * TN_TILES), 512, 0, stream>>>(A8, T8, sumexp);
  finalize_kernel<<<1, 256, 0, stream>>>(sumexp, pos_score, kl, out);
}